// Round 10
// baseline (4740.442 us; speedup 1.0000x reference)
//
#include <hip/hip_runtime.h>

typedef unsigned short u16;
typedef unsigned int u32;
typedef __attribute__((ext_vector_type(8))) short bf16x8;
typedef __attribute__((ext_vector_type(4))) float f32x4;
typedef __attribute__((ext_vector_type(2))) u32 u32x2;
typedef __attribute__((ext_vector_type(4))) u32 u32x4;
typedef const __attribute__((address_space(1))) void* gas1_t;
typedef __attribute__((address_space(3))) void* las3_t;

// Problem dims
#define T_LEN 512
#define B_SZ  64
#define D_SZ  1024
#define H_SZ  1024

// workspace layout (bytes), all 256-aligned
#define OFF_WX    0UL           // 8 MiB  bf16 Wx  [4096][1024]
#define OFF_WH    8388608UL     // 8 MiB  bf16 Wh  [4096][1024]
#define OFF_BIAS  16777216UL    // 16 KiB f32 bias[4096] = bx+bh
#define OFF_FLAGS 16793600UL    // 1 KiB: u32 cntA @ +0, cntB @ +256 (per-half barrier counters)
#define OFF_HBUF  16794624UL    // 256 KiB bf16 hbuf[2][64][1024]
#define OFF_XBF   17056768UL    // 64 MiB bf16 x [32768][1024]
#define OFF_XPROJ 84165632UL    // 256 MiB bf16 xprojP [512][128][64][8][4] ([t][hs][brow][jj][gate])

__device__ __forceinline__ u16 f2bf(float f) {
  u32 u = __builtin_bit_cast(u32, f);
  u += 0x7FFFu + ((u >> 16) & 1u);   // RNE
  return (u16)(u >> 16);
}
__device__ __forceinline__ float bf2f(u16 h) {
  u32 u = ((u32)h) << 16;
  return __builtin_bit_cast(float, u);
}

// ---------- phase 0: conversions ----------
__global__ __launch_bounds__(256) void cvt_f32_bf16(const float* __restrict__ in,
                                                    u16* __restrict__ out, int n) {
  int i = (blockIdx.x * 256 + threadIdx.x) * 4;
  if (i >= n) return;
  float4 v = *(const float4*)(in + i);
  ushort4 o;
  o.x = f2bf(v.x); o.y = f2bf(v.y); o.z = f2bf(v.z); o.w = f2bf(v.w);
  *(ushort4*)(out + i) = o;
}

__global__ __launch_bounds__(256) void bias_add(const float* __restrict__ a,
                                                const float* __restrict__ b,
                                                float* __restrict__ o) {
  int i = blockIdx.x * 256 + threadIdx.x;  // 4096 total
  o[i] = a[i] + b[i];
}

// ---------- phase 1: xproj = x @ Wx^T, written PERMUTED for the lstm reader ----------
// C layout: [t(512)][hs(128)][brow(64)][jj(8)][gate(4)]
__global__ __launch_bounds__(256) void gemm_xproj(const u16* __restrict__ A,
                                                  const u16* __restrict__ Bw,
                                                  u16* __restrict__ C) {
  __shared__ __align__(16) u16 As[128 * 64];
  __shared__ __align__(16) u16 Bs[128 * 64];
  int wg = blockIdx.x;
  int swz = (wg & 7) * 1024 + (wg >> 3);  // XCD-aware bijective (8192 % 8 == 0)
  int mb = swz >> 5;
  int nb = swz & 31;
  int tid = threadIdx.x;
  int lane = tid & 63;
  int w = tid >> 6;
  int wm = w >> 1, wn = w & 1;

  int srow = lane >> 3;
  int scol = (lane & 7) * 8;
  const u16* Abase = A + (size_t)(mb * 128) * 1024;
  const u16* Bbase = Bw + (size_t)(nb * 128) * 1024;

  f32x4 acc[4][4];
#pragma unroll
  for (int i = 0; i < 4; ++i)
#pragma unroll
    for (int j = 0; j < 4; ++j) acc[i][j] = f32x4{0.f, 0.f, 0.f, 0.f};

  for (int k0 = 0; k0 < 1024; k0 += 64) {
#pragma unroll
    for (int r = 0; r < 4; ++r) {
      int chunk = w * 4 + r;
      int row = chunk * 8 + srow;
      __builtin_amdgcn_global_load_lds((gas1_t)(const void*)(Abase + (size_t)row * 1024 + k0 + scol),
                                       (las3_t)(void*)(&As[chunk * 512]), 16, 0, 0);
      __builtin_amdgcn_global_load_lds((gas1_t)(const void*)(Bbase + (size_t)row * 1024 + k0 + scol),
                                       (las3_t)(void*)(&Bs[chunk * 512]), 16, 0, 0);
    }
    __syncthreads();
#pragma unroll
    for (int kk = 0; kk < 64; kk += 32) {
      bf16x8 af[4], bfr[4];
#pragma unroll
      for (int mt = 0; mt < 4; ++mt)
        af[mt] = *(const bf16x8*)&As[(wm * 64 + mt * 16 + (lane & 15)) * 64 + kk + ((lane >> 4) << 3)];
#pragma unroll
      for (int nt = 0; nt < 4; ++nt)
        bfr[nt] = *(const bf16x8*)&Bs[(wn * 64 + nt * 16 + (lane & 15)) * 64 + kk + ((lane >> 4) << 3)];
#pragma unroll
      for (int mt = 0; mt < 4; ++mt)
#pragma unroll
        for (int nt = 0; nt < 4; ++nt)
          acc[mt][nt] = __builtin_amdgcn_mfma_f32_16x16x32_bf16(af[mt], bfr[nt], acc[mt][nt], 0, 0, 0);
    }
    __syncthreads();
  }
  int crowbase = mb * 128 + wm * 64;
  int ccolbase = nb * 128 + wn * 64;
#pragma unroll
  for (int mt = 0; mt < 4; ++mt)
#pragma unroll
    for (int nt = 0; nt < 4; ++nt) {
      int col = ccolbase + nt * 16 + (lane & 15);
      int gate = col >> 10;
      int hc = col & 1023;
      size_t cb = (size_t)(hc >> 3) * 2048 + (size_t)(hc & 7) * 4 + gate;  // hs*64*32 + jj*4 + gate
#pragma unroll
      for (int r = 0; r < 4; ++r) {
        int row = crowbase + mt * 16 + ((lane >> 4) << 2) + r;
        C[(size_t)(row >> 6) * 262144 + cb + (size_t)(row & 63) * 32] = f2bf(acc[mt][nt][r]);
      }
    }
}

// ---------- phase 2: persistent sequential LSTM, HALF-PIPELINED ----------
// 64 WGs x 512 threads. WG owns 16 h-cols for BOTH batch halves; 8 waves
// partition K 8-ways (128 cols each -- NO cg duplication: each WG reads its
// half's h exactly once, 64 KB -> total 8 MB/step LLC, half of R9).
// Per step: phase A (rows 0..31) then phase B (rows 32..63) -- two
// INDEPENDENT recurrences; A's barrier latency hides under B's compute and
// vice versa. Barrier = R9-proven per-half atomic counter at the LLC:
// per-wave store drain -> WG sync -> tid0 fire-and-forget add; await =
// tid0 atomic_add(0) sc0 poll (usually ready: published ~1 phase ago).
__global__ __launch_bounds__(512, 2) void lstm_seq(const u16* __restrict__ xprojP,
                                                   const u16* __restrict__ Whb,
                                                   const float* __restrict__ bias,
                                                   u16* __restrict__ hbuf,
                                                   u32* __restrict__ flags,
                                                   float* __restrict__ out) {
  __shared__ float pacc[64 * 272];  // 64 frags [kq][rt][f], rows padded to 17
#define PIDX(frag, row, col) (((frag) * 272) + (row) * 17 + (col))
  int hw = blockIdx.x;     // 0..63: 16-col slice (cols hw*16 .. hw*16+15)
  int tid = threadIdx.x;   // 0..511
  int lane = tid & 63;
  int kq = tid >> 6;       // wave = K-slice, 0..7 (128 k-cols each)
  int hi8 = (lane >> 4) << 3;

  // Wh fragments, register-resident: wf[f][ks], gate f, k = kq*128 + ks*32
  bf16x8 wf[4][4];
#pragma unroll
  for (int f = 0; f < 4; ++f) {
    int wrow = (f << 10) + (hw << 4) + (lane & 15);  // gate*1024 + hcol
#pragma unroll
    for (int ks = 0; ks < 4; ++ks)
      wf[f][ks] = *(const bf16x8*)&Whb[(size_t)wrow * 1024 + (kq << 7) + ks * 32 + hi8];
  }

  int b = tid >> 4;                  // 0..31 batch row within half
  int jj = tid & 15;                 // 0..15 h-col within WG slice
  int hcol = (hw << 4) + jj;
  float bs0 = bias[hcol], bs1 = bias[1024 + hcol], bs2 = bias[2048 + hcol], bs3 = bias[3072 + hcol];
  float cA = 0.f, cB = 0.f;          // named per-half cell states (rule #20)
  int mI = b >> 4, r16 = b & 15;
  // permuted xproj pointers per half; per-step stride 262144 elems (512 KB)
  const u16* xptA = xprojP + ((size_t)(hcol >> 3) * 64 + b) * 32 + (hcol & 7) * 4;
  const u16* xptB = xptA + 1024;     // +32 rows * 32

  for (int t = 0; t < T_LEN; ++t) {
#pragma unroll
    for (int ph = 0; ph < 2; ++ph) {
      u32* cnt = flags + (ph << 6);
      // ---- await barrier(ph, t): published ~one phase ago -> usually ready ----
      if (t > 0) {
        if (tid == 0) {
          u32 tgt = (u32)(t << 6);   // 64 * t
          u32 zero = 0u, old;
          for (;;) {
            asm volatile("global_atomic_add %0, %1, %2, off sc0\n\ts_waitcnt vmcnt(0)"
                         : "=&v"(old) : "v"(cnt), "v"(zero) : "memory");
            if (old >= tgt) break;
          }
        }
        __syncthreads();
      }
      // ---- coherent h load: 8x dwordx4 sc0 sc1 + vmcnt(0) in ONE asm ----
      const u16* hcur = hbuf + (size_t)(t & 1) * 65536;
      const u16* p0 = hcur + (size_t)((ph << 5) + (lane & 15)) * 1024 + (kq << 7) + hi8;
      const u16* p1 = p0 + 16384;  // +16 rows
      u32x4 r0, r1, r2, r3, r4, r5, r6, r7;
      asm volatile(
          "global_load_dwordx4 %0, %8, off sc0 sc1\n\t"
          "global_load_dwordx4 %1, %8, off offset:64 sc0 sc1\n\t"
          "global_load_dwordx4 %2, %8, off offset:128 sc0 sc1\n\t"
          "global_load_dwordx4 %3, %8, off offset:192 sc0 sc1\n\t"
          "global_load_dwordx4 %4, %9, off sc0 sc1\n\t"
          "global_load_dwordx4 %5, %9, off offset:64 sc0 sc1\n\t"
          "global_load_dwordx4 %6, %9, off offset:128 sc0 sc1\n\t"
          "global_load_dwordx4 %7, %9, off offset:192 sc0 sc1\n\t"
          "s_waitcnt vmcnt(0)"
          : "=&v"(r0), "=&v"(r1), "=&v"(r2), "=&v"(r3),
            "=&v"(r4), "=&v"(r5), "=&v"(r6), "=&v"(r7)
          : "v"(p0), "v"(p1)
          : "memory");
      bf16x8 a0[4] = {__builtin_bit_cast(bf16x8, r0), __builtin_bit_cast(bf16x8, r1),
                      __builtin_bit_cast(bf16x8, r2), __builtin_bit_cast(bf16x8, r3)};
      bf16x8 a1[4] = {__builtin_bit_cast(bf16x8, r4), __builtin_bit_cast(bf16x8, r5),
                      __builtin_bit_cast(bf16x8, r6), __builtin_bit_cast(bf16x8, r7)};
      // xproj (plain cached; compiler inserts waitcnt before use in elementwise)
      const u16* xpt = (ph == 0) ? xptA : xptB;
      u32x2 pd = *(const u32x2*)(xpt + (size_t)t * 262144);

      // ---- MFMA: acc[rt][f] over 4 k-steps ----
      f32x4 acc00 = f32x4{0.f, 0.f, 0.f, 0.f}, acc01 = acc00, acc02 = acc00, acc03 = acc00;
      f32x4 acc10 = acc00, acc11 = acc00, acc12 = acc00, acc13 = acc00;
#pragma unroll
      for (int ks = 0; ks < 4; ++ks) {
        acc00 = __builtin_amdgcn_mfma_f32_16x16x32_bf16(a0[ks], wf[0][ks], acc00, 0, 0, 0);
        acc01 = __builtin_amdgcn_mfma_f32_16x16x32_bf16(a0[ks], wf[1][ks], acc01, 0, 0, 0);
        acc02 = __builtin_amdgcn_mfma_f32_16x16x32_bf16(a0[ks], wf[2][ks], acc02, 0, 0, 0);
        acc03 = __builtin_amdgcn_mfma_f32_16x16x32_bf16(a0[ks], wf[3][ks], acc03, 0, 0, 0);
        acc10 = __builtin_amdgcn_mfma_f32_16x16x32_bf16(a1[ks], wf[0][ks], acc10, 0, 0, 0);
        acc11 = __builtin_amdgcn_mfma_f32_16x16x32_bf16(a1[ks], wf[1][ks], acc11, 0, 0, 0);
        acc12 = __builtin_amdgcn_mfma_f32_16x16x32_bf16(a1[ks], wf[2][ks], acc12, 0, 0, 0);
        acc13 = __builtin_amdgcn_mfma_f32_16x16x32_bf16(a1[ks], wf[3][ks], acc13, 0, 0, 0);
      }
      // ---- per-wave partials -> LDS: frag = kq*8 + rt*4 + f ----
      {
        int rbase = (lane >> 4) << 2;
        int cidx = lane & 15;
        int f0i = kq << 3;
#pragma unroll
        for (int r = 0; r < 4; ++r) {
          pacc[PIDX(f0i + 0, rbase + r, cidx)] = acc00[r];
          pacc[PIDX(f0i + 1, rbase + r, cidx)] = acc01[r];
          pacc[PIDX(f0i + 2, rbase + r, cidx)] = acc02[r];
          pacc[PIDX(f0i + 3, rbase + r, cidx)] = acc03[r];
          pacc[PIDX(f0i + 4, rbase + r, cidx)] = acc10[r];
          pacc[PIDX(f0i + 5, rbase + r, cidx)] = acc11[r];
          pacc[PIDX(f0i + 6, rbase + r, cidx)] = acc12[r];
          pacc[PIDX(f0i + 7, rbase + r, cidx)] = acc13[r];
        }
      }
      __syncthreads();
      // ---- reduce over 8 kq partials per gate ----
      float g[4];
#pragma unroll
      for (int f = 0; f < 4; ++f) {
        float s = 0.f;
#pragma unroll
        for (int k2 = 0; k2 < 8; ++k2)
          s += pacc[PIDX((k2 << 3) + (mI << 2) + f, r16, jj)];
        g[f] = s;
      }
      float gi = g[0] + bf2f((u16)(pd[0] & 0xFFFFu)) + bs0;
      float gf = g[1] + bf2f((u16)(pd[0] >> 16)) + bs1;
      float go = g[2] + bf2f((u16)(pd[1] & 0xFFFFu)) + bs2;
      float gc = g[3] + bf2f((u16)(pd[1] >> 16)) + bs3;
      float iv = 1.f / (1.f + __expf(-gi));
      float fv = 1.f / (1.f + __expf(-gf));
      float ov = 1.f / (1.f + __expf(-go));
      float cv = tanhf(gc);
      float cold = (ph == 0) ? cA : cB;
      float cnew = 1.f / (1.f + __expf(-(fv * cold + iv * cv)));  // nonstandard, per reference
      if (ph == 0) cA = cnew; else cB = cnew;
      float hn = tanhf(cnew) * ov;

      int hrow = (ph << 5) + b;
      if (t == T_LEN - 1) {
        out[(size_t)hrow * 1024 + hcol] = hn;
      } else {
        // write-through h store; wave-level drain; WG sync; tid0 publishes
        u16* hdst = hbuf + (size_t)((t & 1) ^ 1) * 65536 + (size_t)hrow * 1024 + hcol;
        u32 hb = (u32)f2bf(hn);
        asm volatile("global_store_short %0, %1, off sc0 sc1\n\t"
                     "s_waitcnt vmcnt(0)" :: "v"(hdst), "v"(hb) : "memory");
        __syncthreads();  // all stores drained + pacc reads done
        if (tid == 0) {
          u32 one = 1u;
          asm volatile("global_atomic_add %0, %1, off" :: "v"(cnt), "v"(one) : "memory");
        }
      }
    }
  }
}

extern "C" void kernel_launch(void* const* d_in, const int* in_sizes, int n_in,
                              void* d_out, int out_size, void* d_ws, size_t ws_size,
                              hipStream_t stream) {
  const float* x  = (const float*)d_in[0];   // [512][64][1024]
  const float* Wx = (const float*)d_in[1];   // [4][1024][1024]
  const float* bx = (const float*)d_in[2];   // [4][1024]
  const float* Wh = (const float*)d_in[3];   // [4][1024][1024]
  const float* bh = (const float*)d_in[4];   // [4][1024]
  float* out = (float*)d_out;                // [64][1024]
  char* ws = (char*)d_ws;

  u16* wx_bf  = (u16*)(ws + OFF_WX);
  u16* wh_bf  = (u16*)(ws + OFF_WH);
  float* bias = (float*)(ws + OFF_BIAS);
  u32* flags  = (u32*)(ws + OFF_FLAGS);
  u16* hbuf   = (u16*)(ws + OFF_HBUF);
  u16* x_bf   = (u16*)(ws + OFF_XBF);
  u16* xproj  = (u16*)(ws + OFF_XPROJ);

  // per-launch: zero counters (1 KiB) + hbuf slot 0 (h_0 = 0, 128 KiB) -- contiguous
  hipMemsetAsync(ws + OFF_FLAGS, 0, 1024 + 131072, stream);

  cvt_f32_bf16<<<4096, 256, 0, stream>>>(Wx, wx_bf, 4194304);
  cvt_f32_bf16<<<4096, 256, 0, stream>>>(Wh, wh_bf, 4194304);
  bias_add<<<16, 256, 0, stream>>>(bx, bh, bias);
  cvt_f32_bf16<<<32768, 256, 0, stream>>>(x, x_bf, 33554432);
  gemm_xproj<<<8192, 256, 0, stream>>>(x_bf, wx_bf, xproj);
  lstm_seq<<<64, 512, 0, stream>>>(xproj, wh_bf, bias, hbuf, flags, out);
}

// Round 11
// 3463.710 us; speedup vs baseline: 1.3686x; 1.3686x over previous
//
#include <hip/hip_runtime.h>

typedef unsigned short u16;
typedef unsigned int u32;
typedef __attribute__((ext_vector_type(8))) short bf16x8;
typedef __attribute__((ext_vector_type(4))) float f32x4;
typedef __attribute__((ext_vector_type(2))) u32 u32x2;
typedef __attribute__((ext_vector_type(4))) u32 u32x4;
typedef const __attribute__((address_space(1))) void* gas1_t;
typedef __attribute__((address_space(3))) void* las3_t;

// Problem dims
#define T_LEN 512
#define B_SZ  64
#define D_SZ  1024
#define H_SZ  1024

// workspace layout (bytes), all 256-aligned
#define OFF_WX    0UL           // 8 MiB  bf16 Wx  [4096][1024]
#define OFF_WH    8388608UL     // 8 MiB  bf16 Wh  [4096][1024]
#define OFF_BIAS  16777216UL    // 16 KiB f32 bias[4096] = bx+bh
#define OFF_FLAGS 16793600UL    // 1 KiB: u32 cnt0 @ +0, cnt1 @ +256 (per-half barrier counters)
#define OFF_HBUF  16794624UL    // 256 KiB bf16 hbuf[2][64][1024]
#define OFF_XBF   17056768UL    // 64 MiB bf16 x [32768][1024]
#define OFF_XPROJ 84165632UL    // 256 MiB bf16 xprojP [512][128][64][8][4] ([t][hs][brow][jj][gate])

__device__ __forceinline__ u16 f2bf(float f) {
  u32 u = __builtin_bit_cast(u32, f);
  u += 0x7FFFu + ((u >> 16) & 1u);   // RNE
  return (u16)(u >> 16);
}
__device__ __forceinline__ float bf2f(u16 h) {
  u32 u = ((u32)h) << 16;
  return __builtin_bit_cast(float, u);
}

// ---------- phase 0: conversions ----------
__global__ __launch_bounds__(256) void cvt_f32_bf16(const float* __restrict__ in,
                                                    u16* __restrict__ out, int n) {
  int i = (blockIdx.x * 256 + threadIdx.x) * 4;
  if (i >= n) return;
  float4 v = *(const float4*)(in + i);
  ushort4 o;
  o.x = f2bf(v.x); o.y = f2bf(v.y); o.z = f2bf(v.z); o.w = f2bf(v.w);
  *(ushort4*)(out + i) = o;
}

__global__ __launch_bounds__(256) void bias_add(const float* __restrict__ a,
                                                const float* __restrict__ b,
                                                float* __restrict__ o) {
  int i = blockIdx.x * 256 + threadIdx.x;  // 4096 total
  o[i] = a[i] + b[i];
}

// ---------- phase 1: xproj = x @ Wx^T, written PERMUTED for the lstm reader ----------
// C layout: [t(512)][hs(128)][brow(64)][jj(8)][gate(4)]
__global__ __launch_bounds__(256) void gemm_xproj(const u16* __restrict__ A,
                                                  const u16* __restrict__ Bw,
                                                  u16* __restrict__ C) {
  __shared__ __align__(16) u16 As[128 * 64];
  __shared__ __align__(16) u16 Bs[128 * 64];
  int wg = blockIdx.x;
  int swz = (wg & 7) * 1024 + (wg >> 3);  // XCD-aware bijective (8192 % 8 == 0)
  int mb = swz >> 5;
  int nb = swz & 31;
  int tid = threadIdx.x;
  int lane = tid & 63;
  int w = tid >> 6;
  int wm = w >> 1, wn = w & 1;

  int srow = lane >> 3;
  int scol = (lane & 7) * 8;
  const u16* Abase = A + (size_t)(mb * 128) * 1024;
  const u16* Bbase = Bw + (size_t)(nb * 128) * 1024;

  f32x4 acc[4][4];
#pragma unroll
  for (int i = 0; i < 4; ++i)
#pragma unroll
    for (int j = 0; j < 4; ++j) acc[i][j] = f32x4{0.f, 0.f, 0.f, 0.f};

  for (int k0 = 0; k0 < 1024; k0 += 64) {
#pragma unroll
    for (int r = 0; r < 4; ++r) {
      int chunk = w * 4 + r;
      int row = chunk * 8 + srow;
      __builtin_amdgcn_global_load_lds((gas1_t)(const void*)(Abase + (size_t)row * 1024 + k0 + scol),
                                       (las3_t)(void*)(&As[chunk * 512]), 16, 0, 0);
      __builtin_amdgcn_global_load_lds((gas1_t)(const void*)(Bbase + (size_t)row * 1024 + k0 + scol),
                                       (las3_t)(void*)(&Bs[chunk * 512]), 16, 0, 0);
    }
    __syncthreads();
#pragma unroll
    for (int kk = 0; kk < 64; kk += 32) {
      bf16x8 af[4], bfr[4];
#pragma unroll
      for (int mt = 0; mt < 4; ++mt)
        af[mt] = *(const bf16x8*)&As[(wm * 64 + mt * 16 + (lane & 15)) * 64 + kk + ((lane >> 4) << 3)];
#pragma unroll
      for (int nt = 0; nt < 4; ++nt)
        bfr[nt] = *(const bf16x8*)&Bs[(wn * 64 + nt * 16 + (lane & 15)) * 64 + kk + ((lane >> 4) << 3)];
#pragma unroll
      for (int mt = 0; mt < 4; ++mt)
#pragma unroll
        for (int nt = 0; nt < 4; ++nt)
          acc[mt][nt] = __builtin_amdgcn_mfma_f32_16x16x32_bf16(af[mt], bfr[nt], acc[mt][nt], 0, 0, 0);
    }
    __syncthreads();
  }
  int crowbase = mb * 128 + wm * 64;
  int ccolbase = nb * 128 + wn * 64;
#pragma unroll
  for (int mt = 0; mt < 4; ++mt)
#pragma unroll
    for (int nt = 0; nt < 4; ++nt) {
      int col = ccolbase + nt * 16 + (lane & 15);
      int gate = col >> 10;
      int hc = col & 1023;
      size_t cb = (size_t)(hc >> 3) * 2048 + (size_t)(hc & 7) * 4 + gate;  // hs*64*32 + jj*4 + gate
#pragma unroll
      for (int r = 0; r < 4; ++r) {
        int row = crowbase + mt * 16 + ((lane >> 4) << 2) + r;
        C[(size_t)(row >> 6) * 262144 + cb + (size_t)(row & 63) * 32] = f2bf(acc[mt][nt][r]);
      }
    }
}

// ---------- phase 2: persistent sequential LSTM ----------
// 128 WGs x 512 threads. WG = (bh, hw): batch-half bh (32 rows) x 16 h-cols.
// 8 waves partition K 8-WAYS (128 cols each) -- NO duplication: each WG reads
// its half's h exactly once (64 KB) -> 8 MB/step total LLC traffic, half of
// R9, in ONE phase (R10's two-phase chain doubling removed). Each wave
// computes all 4 gates (8 accs); 64-frag LDS reduce (R10-proven mapping).
// Barrier = R9-proven per-half atomic counter at the LLC: per-thread
// write-through h store + xproj(t+1) prefetch + vmcnt(1) drain -> WG sync ->
// tid0 fire-and-forget add -> tid0 atomic_add(0) sc0 poll -> WG sync.
__global__ __launch_bounds__(512, 2) void lstm_seq(const u16* __restrict__ xprojP,
                                                   const u16* __restrict__ Whb,
                                                   const float* __restrict__ bias,
                                                   u16* __restrict__ hbuf,
                                                   u32* __restrict__ flags,
                                                   float* __restrict__ out) {
  __shared__ float pacc[64 * 272];  // 64 frags [kq][rt][f], rows padded to 17
#define PIDX(frag, row, col) (((frag) * 272) + (row) * 17 + (col))
  int wg = blockIdx.x;     // 0..127
  int bh = wg >> 6;        // batch half (independent barrier domain)
  int hw = wg & 63;        // 16-col slice (cols hw*16 .. hw*16+15)
  int tid = threadIdx.x;   // 0..511
  int lane = tid & 63;
  int kq = tid >> 6;       // wave = K-slice, 0..7 (128 k-cols each)
  int kw = kq << 7;        // k base
  int hi8 = (lane >> 4) << 3;

  // Wh fragments, register-resident: wf[f][ks], gate f, k = kq*128 + ks*32
  bf16x8 wf[4][4];
#pragma unroll
  for (int f = 0; f < 4; ++f) {
    int wrow = (f << 10) + (hw << 4) + (lane & 15);  // gate*1024 + out-col
#pragma unroll
    for (int ks = 0; ks < 4; ++ks)
      wf[f][ks] = *(const bf16x8*)&Whb[(size_t)wrow * 1024 + kw + ks * 32 + hi8];
  }

  int b = tid >> 4;                  // 0..31 batch row within half
  int jj = tid & 15;                 // 0..15 h-col within WG slice
  int hrow = (bh << 5) + b;
  int hcol = (hw << 4) + jj;
  float bs0 = bias[hcol], bs1 = bias[1024 + hcol], bs2 = bias[2048 + hcol], bs3 = bias[3072 + hcol];
  float c_state = 0.f;
  int am_row0 = (bh << 5) + (lane & 15);
  int am_row1 = am_row0 + 16;
  int mI = b >> 4, r16 = b & 15;
  u32* cnt = flags + (bh << 6);      // per-half counter, 256 B apart

  // permuted xproj pointer; per-step stride 262144 elems (512 KB)
  const u16* xpt = xprojP + ((size_t)(hcol >> 3) * 64 + hrow) * 32 + (hcol & 7) * 4;
  u32x2 pd = *(const u32x2*)xpt;     // t=0 prefetch (plain cached)

  for (int t = 0; t < T_LEN; ++t) {
    const u16* hcur = hbuf + (size_t)(t & 1) * 65536;
    // ---- coherent h load: 8x dwordx4 sc0 sc1 + vmcnt(0) in ONE asm ----
    // rows am_row0/am_row1 (32 rows), k-cols kq*128..+128 (offsets 0/64/128/192B)
    const u16* p0 = hcur + (size_t)am_row0 * 1024 + kw + hi8;
    const u16* p1 = hcur + (size_t)am_row1 * 1024 + kw + hi8;
    u32x4 r0, r1, r2, r3, r4, r5, r6, r7;
    asm volatile(
        "global_load_dwordx4 %0, %8, off sc0 sc1\n\t"
        "global_load_dwordx4 %1, %8, off offset:64 sc0 sc1\n\t"
        "global_load_dwordx4 %2, %8, off offset:128 sc0 sc1\n\t"
        "global_load_dwordx4 %3, %8, off offset:192 sc0 sc1\n\t"
        "global_load_dwordx4 %4, %9, off sc0 sc1\n\t"
        "global_load_dwordx4 %5, %9, off offset:64 sc0 sc1\n\t"
        "global_load_dwordx4 %6, %9, off offset:128 sc0 sc1\n\t"
        "global_load_dwordx4 %7, %9, off offset:192 sc0 sc1\n\t"
        "s_waitcnt vmcnt(0)"
        : "=&v"(r0), "=&v"(r1), "=&v"(r2), "=&v"(r3),
          "=&v"(r4), "=&v"(r5), "=&v"(r6), "=&v"(r7)
        : "v"(p0), "v"(p1)
        : "memory");
    bf16x8 a0[4] = {__builtin_bit_cast(bf16x8, r0), __builtin_bit_cast(bf16x8, r1),
                    __builtin_bit_cast(bf16x8, r2), __builtin_bit_cast(bf16x8, r3)};
    bf16x8 a1[4] = {__builtin_bit_cast(bf16x8, r4), __builtin_bit_cast(bf16x8, r5),
                    __builtin_bit_cast(bf16x8, r6), __builtin_bit_cast(bf16x8, r7)};

    // ---- MFMA: 8 accs (2 row-frags x 4 gates) over 4 k-steps ----
    f32x4 acc00 = f32x4{0.f, 0.f, 0.f, 0.f}, acc01 = acc00, acc02 = acc00, acc03 = acc00;
    f32x4 acc10 = acc00, acc11 = acc00, acc12 = acc00, acc13 = acc00;
#pragma unroll
    for (int ks = 0; ks < 4; ++ks) {
      acc00 = __builtin_amdgcn_mfma_f32_16x16x32_bf16(a0[ks], wf[0][ks], acc00, 0, 0, 0);
      acc01 = __builtin_amdgcn_mfma_f32_16x16x32_bf16(a0[ks], wf[1][ks], acc01, 0, 0, 0);
      acc02 = __builtin_amdgcn_mfma_f32_16x16x32_bf16(a0[ks], wf[2][ks], acc02, 0, 0, 0);
      acc03 = __builtin_amdgcn_mfma_f32_16x16x32_bf16(a0[ks], wf[3][ks], acc03, 0, 0, 0);
      acc10 = __builtin_amdgcn_mfma_f32_16x16x32_bf16(a1[ks], wf[0][ks], acc10, 0, 0, 0);
      acc11 = __builtin_amdgcn_mfma_f32_16x16x32_bf16(a1[ks], wf[1][ks], acc11, 0, 0, 0);
      acc12 = __builtin_amdgcn_mfma_f32_16x16x32_bf16(a1[ks], wf[2][ks], acc12, 0, 0, 0);
      acc13 = __builtin_amdgcn_mfma_f32_16x16x32_bf16(a1[ks], wf[3][ks], acc13, 0, 0, 0);
    }
    // ---- per-wave partials -> LDS: frag = kq*8 + rt*4 + f ----
    {
      int rbase = (lane >> 4) << 2;
      int cidx = lane & 15;
      int f0i = kq << 3;
#pragma unroll
      for (int r = 0; r < 4; ++r) {
        pacc[PIDX(f0i + 0, rbase + r, cidx)] = acc00[r];
        pacc[PIDX(f0i + 1, rbase + r, cidx)] = acc01[r];
        pacc[PIDX(f0i + 2, rbase + r, cidx)] = acc02[r];
        pacc[PIDX(f0i + 3, rbase + r, cidx)] = acc03[r];
        pacc[PIDX(f0i + 4, rbase + r, cidx)] = acc10[r];
        pacc[PIDX(f0i + 5, rbase + r, cidx)] = acc11[r];
        pacc[PIDX(f0i + 6, rbase + r, cidx)] = acc12[r];
        pacc[PIDX(f0i + 7, rbase + r, cidx)] = acc13[r];
      }
    }
    __syncthreads();
    // ---- reduce over 8 kq partials per gate ----
    float g[4];
#pragma unroll
    for (int f = 0; f < 4; ++f) {
      float s = 0.f;
#pragma unroll
      for (int k2 = 0; k2 < 8; ++k2)
        s += pacc[PIDX((k2 << 3) + (mI << 2) + f, r16, jj)];
      g[f] = s;
    }
    // tie the prefetched xproj dwords to a vmcnt before use (rule #18)
    asm volatile("s_waitcnt vmcnt(0)" : "+v"(pd));
    float gi = g[0] + bf2f((u16)(pd[0] & 0xFFFFu)) + bs0;
    float gf = g[1] + bf2f((u16)(pd[0] >> 16)) + bs1;
    float go = g[2] + bf2f((u16)(pd[1] & 0xFFFFu)) + bs2;
    float gc = g[3] + bf2f((u16)(pd[1] >> 16)) + bs3;
    float iv = 1.f / (1.f + __expf(-gi));
    float fv = 1.f / (1.f + __expf(-gf));
    float ov = 1.f / (1.f + __expf(-go));
    float cv = tanhf(gc);
    c_state = 1.f / (1.f + __expf(-(fv * c_state + iv * cv)));  // nonstandard, per reference
    float hn = tanhf(c_state) * ov;

    if (t == T_LEN - 1) {
      out[(size_t)hrow * 1024 + hcol] = hn;
    } else {
      // h store (write-through) + xproj(t+1) prefetch + in-order counted drain:
      // vmcnt(1) retires the OLDER store; the load stays in flight through the poll.
      u16* hdst = hbuf + (size_t)((t & 1) ^ 1) * 65536 + (size_t)hrow * 1024 + hcol;
      const u16* xnext = xpt + (size_t)(t + 1) * 262144;
      u32 hb = (u32)f2bf(hn);
      asm volatile(
          "global_store_short %1, %3, off sc0 sc1\n\t"
          "global_load_dwordx2 %0, %2, off\n\t"
          "s_waitcnt vmcnt(1)"
          : "=&v"(pd)
          : "v"(hdst), "v"(xnext), "v"(hb)
          : "memory");
      __syncthreads();  // all 8 waves' stores drained; pacc reads done
      // publish: fire-and-forget atomic increment (performed at the LLC)
      if (tid == 0) {
        u32 one = 1u;
        asm volatile("global_atomic_add %0, %1, off" :: "v"(cnt), "v"(one) : "memory");
        // poll: atomic read-at-LLC (add 0, sc0 returns old). One line, LLC-resident.
        u32 tgt64 = (u32)((t + 1) << 6);
        u32 zero = 0u;
        u32 old;
        for (;;) {
          asm volatile("global_atomic_add %0, %1, %2, off sc0\n\ts_waitcnt vmcnt(0)"
                       : "=&v"(old) : "v"(cnt), "v"(zero) : "memory");
          if (old >= tgt64) break;
        }
      }
      __syncthreads();
    }
  }
}

extern "C" void kernel_launch(void* const* d_in, const int* in_sizes, int n_in,
                              void* d_out, int out_size, void* d_ws, size_t ws_size,
                              hipStream_t stream) {
  const float* x  = (const float*)d_in[0];   // [512][64][1024]
  const float* Wx = (const float*)d_in[1];   // [4][1024][1024]
  const float* bx = (const float*)d_in[2];   // [4][1024]
  const float* Wh = (const float*)d_in[3];   // [4][1024][1024]
  const float* bh = (const float*)d_in[4];   // [4][1024]
  float* out = (float*)d_out;                // [64][1024]
  char* ws = (char*)d_ws;

  u16* wx_bf  = (u16*)(ws + OFF_WX);
  u16* wh_bf  = (u16*)(ws + OFF_WH);
  float* bias = (float*)(ws + OFF_BIAS);
  u32* flags  = (u32*)(ws + OFF_FLAGS);
  u16* hbuf   = (u16*)(ws + OFF_HBUF);
  u16* x_bf   = (u16*)(ws + OFF_XBF);
  u16* xproj  = (u16*)(ws + OFF_XPROJ);

  // per-launch: zero counters (1 KiB) + hbuf slot 0 (h_0 = 0, 128 KiB) -- contiguous
  hipMemsetAsync(ws + OFF_FLAGS, 0, 1024 + 131072, stream);

  cvt_f32_bf16<<<4096, 256, 0, stream>>>(Wx, wx_bf, 4194304);
  cvt_f32_bf16<<<4096, 256, 0, stream>>>(Wh, wh_bf, 4194304);
  bias_add<<<16, 256, 0, stream>>>(bx, bh, bias);
  cvt_f32_bf16<<<32768, 256, 0, stream>>>(x, x_bf, 33554432);
  gemm_xproj<<<8192, 256, 0, stream>>>(x_bf, wx_bf, xproj);
  lstm_seq<<<128, 512, 0, stream>>>(xproj, wh_bf, bias, hbuf, flags, out);
}

// Round 12
// 3434.637 us; speedup vs baseline: 1.3802x; 1.0085x over previous
//
#include <hip/hip_runtime.h>

typedef unsigned short u16;
typedef unsigned int u32;
typedef __attribute__((ext_vector_type(8))) short bf16x8;
typedef __attribute__((ext_vector_type(4))) float f32x4;
typedef __attribute__((ext_vector_type(2))) u32 u32x2;
typedef const __attribute__((address_space(1))) void* gas1_t;
typedef __attribute__((address_space(3))) void* las3_t;

// Problem dims
#define T_LEN 512
#define B_SZ  64
#define D_SZ  1024
#define H_SZ  1024

// workspace layout (bytes), all 256-aligned
#define OFF_WX    0UL           // 8 MiB  bf16 Wx  [4096][1024]
#define OFF_WH    8388608UL     // 8 MiB  bf16 Wh  [4096][1024]
#define OFF_BIAS  16777216UL    // 16 KiB f32 bias[4096] = bx+bh
#define OFF_FLAGS 16793600UL    // 1 KiB: u32 cnt0 @ +0, cnt1 @ +256 (per-half barrier counters)
#define OFF_HROLL 16794624UL    // 64 MiB bf16 hroll[512][64][1024] (slot t = h input of step t)
#define OFF_XBF   83903488UL    // 64 MiB bf16 x [32768][1024]
#define OFF_XPROJ 151012352UL   // 256 MiB bf16 xprojP [512][128][64][8][4] ([t][hs][brow][jj][gate])

__device__ __forceinline__ u16 f2bf(float f) {
  u32 u = __builtin_bit_cast(u32, f);
  u += 0x7FFFu + ((u >> 16) & 1u);   // RNE
  return (u16)(u >> 16);
}
__device__ __forceinline__ float bf2f(u16 h) {
  u32 u = ((u32)h) << 16;
  return __builtin_bit_cast(float, u);
}

// ---------- phase 0: conversions ----------
__global__ __launch_bounds__(256) void cvt_f32_bf16(const float* __restrict__ in,
                                                    u16* __restrict__ out, int n) {
  int i = (blockIdx.x * 256 + threadIdx.x) * 4;
  if (i >= n) return;
  float4 v = *(const float4*)(in + i);
  ushort4 o;
  o.x = f2bf(v.x); o.y = f2bf(v.y); o.z = f2bf(v.z); o.w = f2bf(v.w);
  *(ushort4*)(out + i) = o;
}

__global__ __launch_bounds__(256) void bias_add(const float* __restrict__ a,
                                                const float* __restrict__ b,
                                                float* __restrict__ o) {
  int i = blockIdx.x * 256 + threadIdx.x;  // 4096 total
  o[i] = a[i] + b[i];
}

// ---------- phase 1: xproj = x @ Wx^T, written PERMUTED for the lstm reader ----------
// C layout: [t(512)][hs(128)][brow(64)][jj(8)][gate(4)]
__global__ __launch_bounds__(256) void gemm_xproj(const u16* __restrict__ A,
                                                  const u16* __restrict__ Bw,
                                                  u16* __restrict__ C) {
  __shared__ __align__(16) u16 As[128 * 64];
  __shared__ __align__(16) u16 Bs[128 * 64];
  int wg = blockIdx.x;
  int swz = (wg & 7) * 1024 + (wg >> 3);  // XCD-aware bijective (8192 % 8 == 0)
  int mb = swz >> 5;
  int nb = swz & 31;
  int tid = threadIdx.x;
  int lane = tid & 63;
  int w = tid >> 6;
  int wm = w >> 1, wn = w & 1;

  int srow = lane >> 3;
  int scol = (lane & 7) * 8;
  const u16* Abase = A + (size_t)(mb * 128) * 1024;
  const u16* Bbase = Bw + (size_t)(nb * 128) * 1024;

  f32x4 acc[4][4];
#pragma unroll
  for (int i = 0; i < 4; ++i)
#pragma unroll
    for (int j = 0; j < 4; ++j) acc[i][j] = f32x4{0.f, 0.f, 0.f, 0.f};

  for (int k0 = 0; k0 < 1024; k0 += 64) {
#pragma unroll
    for (int r = 0; r < 4; ++r) {
      int chunk = w * 4 + r;
      int row = chunk * 8 + srow;
      __builtin_amdgcn_global_load_lds((gas1_t)(const void*)(Abase + (size_t)row * 1024 + k0 + scol),
                                       (las3_t)(void*)(&As[chunk * 512]), 16, 0, 0);
      __builtin_amdgcn_global_load_lds((gas1_t)(const void*)(Bbase + (size_t)row * 1024 + k0 + scol),
                                       (las3_t)(void*)(&Bs[chunk * 512]), 16, 0, 0);
    }
    __syncthreads();
#pragma unroll
    for (int kk = 0; kk < 64; kk += 32) {
      bf16x8 af[4], bfr[4];
#pragma unroll
      for (int mt = 0; mt < 4; ++mt)
        af[mt] = *(const bf16x8*)&As[(wm * 64 + mt * 16 + (lane & 15)) * 64 + kk + ((lane >> 4) << 3)];
#pragma unroll
      for (int nt = 0; nt < 4; ++nt)
        bfr[nt] = *(const bf16x8*)&Bs[(wn * 64 + nt * 16 + (lane & 15)) * 64 + kk + ((lane >> 4) << 3)];
#pragma unroll
      for (int mt = 0; mt < 4; ++mt)
#pragma unroll
        for (int nt = 0; nt < 4; ++nt)
          acc[mt][nt] = __builtin_amdgcn_mfma_f32_16x16x32_bf16(af[mt], bfr[nt], acc[mt][nt], 0, 0, 0);
    }
    __syncthreads();
  }
  int crowbase = mb * 128 + wm * 64;
  int ccolbase = nb * 128 + wn * 64;
#pragma unroll
  for (int mt = 0; mt < 4; ++mt)
#pragma unroll
    for (int nt = 0; nt < 4; ++nt) {
      int col = ccolbase + nt * 16 + (lane & 15);
      int gate = col >> 10;
      int hc = col & 1023;
      size_t cb = (size_t)(hc >> 3) * 2048 + (size_t)(hc & 7) * 4 + gate;  // hs*64*32 + jj*4 + gate
#pragma unroll
      for (int r = 0; r < 4; ++r) {
        int row = crowbase + mt * 16 + ((lane >> 4) << 2) + r;
        C[(size_t)(row >> 6) * 262144 + cb + (size_t)(row & 63) * 32] = f2bf(acc[mt][nt][r]);
      }
    }
}

// ---------- phase 2: persistent sequential LSTM ----------
// R11 structure (128 WGs x 512 threads, 8-way K-partition, one phase, atomic
// counter barrier) + ROLLING h buffer with NORMAL CACHED h loads:
// slot t+1 is written (write-through sc0 sc1) during step t and read only
// after barrier t -> addresses are virgin per launch, so cached lines can
// only enter L1/L2 via post-release demand reads (staleness impossible;
// proven by R4/R6). Each XCD's L2 dedups its ~16 WGs' reads: h-broadcast
// LLC traffic 8 MB/step -> ~1 MB/step, and most WGs L2-hit the h load.
__global__ __launch_bounds__(512, 2) void lstm_seq(const u16* __restrict__ xprojP,
                                                   const u16* __restrict__ Whb,
                                                   const float* __restrict__ bias,
                                                   u16* __restrict__ hroll,
                                                   u32* __restrict__ flags,
                                                   float* __restrict__ out) {
  __shared__ float pacc[64 * 272];  // 64 frags [kq][rt][f], rows padded to 17
#define PIDX(frag, row, col) (((frag) * 272) + (row) * 17 + (col))
  int wg = blockIdx.x;     // 0..127
  int bh = wg >> 6;        // batch half (independent barrier domain)
  int hw = wg & 63;        // 16-col slice (cols hw*16 .. hw*16+15)
  int tid = threadIdx.x;   // 0..511
  int lane = tid & 63;
  int kq = tid >> 6;       // wave = K-slice, 0..7 (128 k-cols each)
  int kw = kq << 7;        // k base
  int hi8 = (lane >> 4) << 3;

  // Wh fragments, register-resident: wf[f][ks], gate f, k = kq*128 + ks*32
  bf16x8 wf[4][4];
#pragma unroll
  for (int f = 0; f < 4; ++f) {
    int wrow = (f << 10) + (hw << 4) + (lane & 15);  // gate*1024 + out-col
#pragma unroll
    for (int ks = 0; ks < 4; ++ks)
      wf[f][ks] = *(const bf16x8*)&Whb[(size_t)wrow * 1024 + kw + ks * 32 + hi8];
  }

  int b = tid >> 4;                  // 0..31 batch row within half
  int jj = tid & 15;                 // 0..15 h-col within WG slice
  int hrow = (bh << 5) + b;
  int hcol = (hw << 4) + jj;
  float bs0 = bias[hcol], bs1 = bias[1024 + hcol], bs2 = bias[2048 + hcol], bs3 = bias[3072 + hcol];
  float c_state = 0.f;
  int am_row0 = (bh << 5) + (lane & 15);
  int am_row1 = am_row0 + 16;
  int mI = b >> 4, r16 = b & 15;
  u32* cnt = flags + (bh << 6);      // per-half counter, 256 B apart

  // permuted xproj pointer; per-step stride 262144 elems (512 KB)
  const u16* xpt = xprojP + ((size_t)(hcol >> 3) * 64 + hrow) * 32 + (hcol & 7) * 4;
  u32x2 pd = *(const u32x2*)xpt;     // t=0 prefetch (plain cached)

  for (int t = 0; t < T_LEN; ++t) {
    // ---- h load: NORMAL CACHED from rolling slot t (virgin addresses) ----
    const u16* hcur = hroll + (size_t)t * 65536;
    const u16* p0 = hcur + (size_t)am_row0 * 1024 + kw + hi8;
    const u16* p1 = hcur + (size_t)am_row1 * 1024 + kw + hi8;
    bf16x8 a0[4], a1[4];
#pragma unroll
    for (int ks = 0; ks < 4; ++ks) {
      a0[ks] = *(const bf16x8*)(p0 + ks * 32);
      a1[ks] = *(const bf16x8*)(p1 + ks * 32);
    }

    // ---- MFMA: 8 accs (2 row-frags x 4 gates) over 4 k-steps ----
    f32x4 acc00 = f32x4{0.f, 0.f, 0.f, 0.f}, acc01 = acc00, acc02 = acc00, acc03 = acc00;
    f32x4 acc10 = acc00, acc11 = acc00, acc12 = acc00, acc13 = acc00;
#pragma unroll
    for (int ks = 0; ks < 4; ++ks) {
      acc00 = __builtin_amdgcn_mfma_f32_16x16x32_bf16(a0[ks], wf[0][ks], acc00, 0, 0, 0);
      acc01 = __builtin_amdgcn_mfma_f32_16x16x32_bf16(a0[ks], wf[1][ks], acc01, 0, 0, 0);
      acc02 = __builtin_amdgcn_mfma_f32_16x16x32_bf16(a0[ks], wf[2][ks], acc02, 0, 0, 0);
      acc03 = __builtin_amdgcn_mfma_f32_16x16x32_bf16(a0[ks], wf[3][ks], acc03, 0, 0, 0);
      acc10 = __builtin_amdgcn_mfma_f32_16x16x32_bf16(a1[ks], wf[0][ks], acc10, 0, 0, 0);
      acc11 = __builtin_amdgcn_mfma_f32_16x16x32_bf16(a1[ks], wf[1][ks], acc11, 0, 0, 0);
      acc12 = __builtin_amdgcn_mfma_f32_16x16x32_bf16(a1[ks], wf[2][ks], acc12, 0, 0, 0);
      acc13 = __builtin_amdgcn_mfma_f32_16x16x32_bf16(a1[ks], wf[3][ks], acc13, 0, 0, 0);
    }
    // ---- per-wave partials -> LDS: frag = kq*8 + rt*4 + f ----
    {
      int rbase = (lane >> 4) << 2;
      int cidx = lane & 15;
      int f0i = kq << 3;
#pragma unroll
      for (int r = 0; r < 4; ++r) {
        pacc[PIDX(f0i + 0, rbase + r, cidx)] = acc00[r];
        pacc[PIDX(f0i + 1, rbase + r, cidx)] = acc01[r];
        pacc[PIDX(f0i + 2, rbase + r, cidx)] = acc02[r];
        pacc[PIDX(f0i + 3, rbase + r, cidx)] = acc03[r];
        pacc[PIDX(f0i + 4, rbase + r, cidx)] = acc10[r];
        pacc[PIDX(f0i + 5, rbase + r, cidx)] = acc11[r];
        pacc[PIDX(f0i + 6, rbase + r, cidx)] = acc12[r];
        pacc[PIDX(f0i + 7, rbase + r, cidx)] = acc13[r];
      }
    }
    __syncthreads();
    // ---- reduce over 8 kq partials per gate ----
    float g[4];
#pragma unroll
    for (int f = 0; f < 4; ++f) {
      float s = 0.f;
#pragma unroll
      for (int k2 = 0; k2 < 8; ++k2)
        s += pacc[PIDX((k2 << 3) + (mI << 2) + f, r16, jj)];
      g[f] = s;
    }
    // tie the prefetched xproj dwords to a vmcnt before use (rule #18)
    asm volatile("s_waitcnt vmcnt(0)" : "+v"(pd));
    float gi = g[0] + bf2f((u16)(pd[0] & 0xFFFFu)) + bs0;
    float gf = g[1] + bf2f((u16)(pd[0] >> 16)) + bs1;
    float go = g[2] + bf2f((u16)(pd[1] & 0xFFFFu)) + bs2;
    float gc = g[3] + bf2f((u16)(pd[1] >> 16)) + bs3;
    float iv = 1.f / (1.f + __expf(-gi));
    float fv = 1.f / (1.f + __expf(-gf));
    float ov = 1.f / (1.f + __expf(-go));
    float cv = tanhf(gc);
    c_state = 1.f / (1.f + __expf(-(fv * c_state + iv * cv)));  // nonstandard, per reference
    float hn = tanhf(c_state) * ov;

    if (t == T_LEN - 1) {
      out[(size_t)hrow * 1024 + hcol] = hn;
    } else {
      // h store (write-through to slot t+1) + xproj(t+1) prefetch + counted
      // drain: vmcnt(1) retires the OLDER store; load flies through the poll.
      u16* hdst = hroll + (size_t)(t + 1) * 65536 + (size_t)hrow * 1024 + hcol;
      const u16* xnext = xpt + (size_t)(t + 1) * 262144;
      u32 hb = (u32)f2bf(hn);
      asm volatile(
          "global_store_short %1, %3, off sc0 sc1\n\t"
          "global_load_dwordx2 %0, %2, off\n\t"
          "s_waitcnt vmcnt(1)"
          : "=&v"(pd)
          : "v"(hdst), "v"(xnext), "v"(hb)
          : "memory");
      __syncthreads();  // all 8 waves' stores drained; pacc reads done
      // publish: fire-and-forget atomic increment (performed at the LLC)
      if (tid == 0) {
        u32 one = 1u;
        asm volatile("global_atomic_add %0, %1, off" :: "v"(cnt), "v"(one) : "memory");
        // poll: atomic read-at-LLC (add 0, sc0 returns old). One line, LLC-resident.
        u32 tgt64 = (u32)((t + 1) << 6);
        u32 zero = 0u;
        u32 old;
        for (;;) {
          asm volatile("global_atomic_add %0, %1, %2, off sc0\n\ts_waitcnt vmcnt(0)"
                       : "=&v"(old) : "v"(cnt), "v"(zero) : "memory");
          if (old >= tgt64) break;
        }
      }
      __syncthreads();
    }
  }
}

extern "C" void kernel_launch(void* const* d_in, const int* in_sizes, int n_in,
                              void* d_out, int out_size, void* d_ws, size_t ws_size,
                              hipStream_t stream) {
  const float* x  = (const float*)d_in[0];   // [512][64][1024]
  const float* Wx = (const float*)d_in[1];   // [4][1024][1024]
  const float* bx = (const float*)d_in[2];   // [4][1024]
  const float* Wh = (const float*)d_in[3];   // [4][1024][1024]
  const float* bh = (const float*)d_in[4];   // [4][1024]
  float* out = (float*)d_out;                // [64][1024]
  char* ws = (char*)d_ws;

  u16* wx_bf  = (u16*)(ws + OFF_WX);
  u16* wh_bf  = (u16*)(ws + OFF_WH);
  float* bias = (float*)(ws + OFF_BIAS);
  u32* flags  = (u32*)(ws + OFF_FLAGS);
  u16* hroll  = (u16*)(ws + OFF_HROLL);
  u16* x_bf   = (u16*)(ws + OFF_XBF);
  u16* xproj  = (u16*)(ws + OFF_XPROJ);

  // per-launch: zero counters (1 KiB) + rolling slot 0 (h_0 = 0, 128 KiB) -- contiguous
  hipMemsetAsync(ws + OFF_FLAGS, 0, 1024 + 131072, stream);

  cvt_f32_bf16<<<4096, 256, 0, stream>>>(Wx, wx_bf, 4194304);
  cvt_f32_bf16<<<4096, 256, 0, stream>>>(Wh, wh_bf, 4194304);
  bias_add<<<16, 256, 0, stream>>>(bx, bh, bias);
  cvt_f32_bf16<<<32768, 256, 0, stream>>>(x, x_bf, 33554432);
  gemm_xproj<<<8192, 256, 0, stream>>>(x_bf, wx_bf, xproj);
  lstm_seq<<<128, 512, 0, stream>>>(xproj, wh_bf, bias, hroll, flags, out);
}